// Round 6
// baseline (462.328 us; speedup 1.0000x reference)
//
#include <hip/hip_runtime.h>
#include <math.h>

#define EPSV   1e-5f

typedef __attribute__((ext_vector_type(8))) short bf16x8;
typedef __attribute__((ext_vector_type(4))) float f32x4;

__device__ __forceinline__ short f2bf(float f){
    unsigned u = __float_as_uint(f);
    u += 0x7fffu + ((u >> 16) & 1u);
    return (short)(u >> 16);
}
__device__ __forceinline__ f32x4 mfma16(bf16x8 a, bf16x8 b, f32x4 c){
    return __builtin_amdgcn_mfma_f32_16x16x32_bf16(a, b, c, 0, 0, 0);
}
__device__ __forceinline__ bf16x8 ldfrag(const short* base, int row, int kbyte, int rowBytes){
    int byte = row * rowBytes + kbyte;
    byte ^= (row & 7) << 4;
    return *(const bf16x8*)((const char*)base + byte);
}
__device__ __forceinline__ bf16x8 ldfragG(const short* base, int row, int kbyte, int rowBytes){
    return *(const bf16x8*)((const char*)base + (size_t)row * rowBytes + kbyte);
}
__device__ __forceinline__ void stswz(short* base, int row, int col, int rowBytes, short v){
    int byte = row * rowBytes + col * 2;
    byte ^= (row & 7) << 4;
    *(short*)((char*)base + byte) = v;
}

// ---------------------------------------------------------------------------
// one-shot fp32 -> bf16 weight conversion (dst offsets match wb layout)
// ---------------------------------------------------------------------------
__global__ __launch_bounds__(256) void cvt_all(
    const float* __restrict__ ipw, const float* __restrict__ opw,
    const float* __restrict__ fw1, const float* __restrict__ fw2,
    short* __restrict__ dst)
{
    int i = (blockIdx.x * 256 + threadIdx.x) * 4;
    if (i >= 1179648) return;
    const float* src; int off;
    if (i < 98304)       { src = ipw; off = i; }
    else if (i < 131072) { src = opw; off = i - 98304; }
    else if (i < 655360) { src = fw1; off = i - 131072; }
    else                 { src = fw2; off = i - 655360; }
    float4 v = *(const float4*)(src + off);
    short4 s;
    s.x = f2bf(v.x); s.y = f2bf(v.y); s.z = f2bf(v.z); s.w = f2bf(v.w);
    *(short4*)(dst + i) = s;
}

// ---------------------------------------------------------------------------
// GCN branch (gcn_small folded in as the last block)
// ---------------------------------------------------------------------------
__global__ __launch_bounds__(256) void gcn_all(
    const float* __restrict__ x,
    const float* __restrict__ Wg1, const float* __restrict__ bg1,
    const float* __restrict__ Wg2, const float* __restrict__ bg2,
    float* __restrict__ xgcn)
{
    int tid = threadIdx.x;
    if (blockIdx.x == 18432) {
        __shared__ float xgm[9];
        __shared__ float h1s[64];
        if (tid < 9) {
            float s = 0.f;
            for (int r = 0; r < 9; ++r) {
                const float* xp = x + (r * 9 + tid) * 7;
                #pragma unroll
                for (int f = 0; f < 7; ++f) s += xp[f];
            }
            xgm[tid] = s * (1.f / 63.f);
        }
        __syncthreads();
        if (tid < 64) {
            float acc = bg1[tid];
            #pragma unroll
            for (int j = 0; j < 9; ++j) acc += xgm[j] * Wg1[j * 64 + tid];
            h1s[tid] = fmaxf(acc, 0.f);
        }
        __syncthreads();
        if (tid < 128) {
            float acc = bg2[tid];
            #pragma unroll 8
            for (int c = 0; c < 64; ++c) acc += h1s[c] * Wg2[c * 128 + tid];
            float v = fmaxf(acc, 0.f);
            for (int r = 0; r < 9; ++r) xgcn[r * 128 + tid] = v;
        }
        return;
    }

    __shared__ float xg[2][9];
    __shared__ float h1[2][64];
    int ri = tid >> 7;
    int tr = tid & 127;
    int row = blockIdx.x * 2 + ri;

    if (tr < 9) {
        const float* xp = x + (row * 9 + tr) * 7;
        float s = 0.f;
        #pragma unroll
        for (int f = 0; f < 7; ++f) s += xp[f];
        xg[ri][tr] = s * (1.f / 7.f);
    }
    __syncthreads();
    if (tr < 64) {
        float acc = bg1[tr];
        #pragma unroll
        for (int j = 0; j < 9; ++j) acc += xg[ri][j] * Wg1[j * 64 + tr];
        h1[ri][tr] = fmaxf(acc, 0.f);
    }
    __syncthreads();
    if (row >= 9) {
        float acc = bg2[tr];
        #pragma unroll 8
        for (int c = 0; c < 64; ++c) acc += h1[ri][c] * Wg2[c * 128 + tr];
        xgcn[row * 128 + tr] = fmaxf(acc, 0.f);
    }
}

// ---------------------------------------------------------------------------
// Conv branch (unchanged)
// ---------------------------------------------------------------------------
__global__ __launch_bounds__(256) void conv_branch(
    const float* __restrict__ x,
    const float* __restrict__ w1, const float* __restrict__ cb1,
    const float* __restrict__ w2, const float* __restrict__ cb2,
    const float* __restrict__ bng, const float* __restrict__ bnb,
    const float* __restrict__ bnm, const float* __restrict__ bnv,
    float* __restrict__ sbuf)
{
    __shared__ float xm[7 * 40];
    __shared__ float w1s[64 * 35];
    __shared__ float o1[64 * 38];
    int tid = threadIdx.x;
    int b = blockIdx.x;

    for (int idx = tid; idx < 7 * 40; idx += 256) xm[idx] = 0.f;
    for (int idx = tid; idx < 64 * 38; idx += 256) o1[idx] = 0.f;
    for (int idx = tid; idx < 2240; idx += 256) w1s[idx] = w1[idx];
    __syncthreads();

    const float* xb = x + (size_t)b * 2268;
    for (int idx = tid; idx < 252; idx += 256) {
        int f = idx / 36, l = idx - f * 36;
        float s = 0.f;
        #pragma unroll
        for (int n = 0; n < 9; ++n) s += xb[n * 252 + idx];
        xm[f * 40 + l + 2] = s * (1.f / 9.f);
    }
    __syncthreads();

    {
        int o = tid & 63, lh = tid >> 6;
        int l0 = lh * 9;
        float acc[9];
        float bias = cb1[o];
        #pragma unroll
        for (int r = 0; r < 9; ++r) acc[r] = bias;
        #pragma unroll
        for (int i = 0; i < 7; ++i) {
            #pragma unroll
            for (int k = 0; k < 5; ++k) {
                float w = w1s[o * 35 + i * 5 + k];
                const float* xrow = &xm[i * 40 + l0 + k];
                #pragma unroll
                for (int r = 0; r < 9; ++r) acc[r] += w * xrow[r];
            }
        }
        #pragma unroll
        for (int r = 0; r < 9; ++r) o1[o * 38 + l0 + r + 1] = acc[r];
    }
    __syncthreads();

    {
        int c = tid & 127, lh = tid >> 7;
        int l0 = lh * 18;
        float acc[18];
        #pragma unroll
        for (int r = 0; r < 18; ++r) acc[r] = 0.f;
        const float* w2c = w2 + c * 192;
        for (int i = 0; i < 64; ++i) {
            float wa = w2c[i * 3 + 0], wb = w2c[i * 3 + 1], wc = w2c[i * 3 + 2];
            const float* orow = &o1[i * 38 + l0];
            #pragma unroll
            for (int r = 0; r < 18; ++r)
                acc[r] += wa * orow[r] + wb * orow[r + 1] + wc * orow[r + 2];
        }
        float scale = bng[c] * rsqrtf(bnv[c] + EPSV);
        float shift = bnb[c] - bnm[c] * scale;
        float bias  = cb2[c];
        float* sb = sbuf + ((size_t)b * 36 + l0) * 128 + c;
        #pragma unroll
        for (int r = 0; r < 18; ++r)
            sb[r * 128] = (acc[r] + bias) * scale + shift;
    }
}

// ---------------------------------------------------------------------------
// Attention + out-proj + residual + LN1 (in-register), per batch element.
// ---------------------------------------------------------------------------
__global__ __launch_bounds__(256, 2) void attn_mfma(
    float* __restrict__ sbuf,
    const short* __restrict__ ipwb, const float* __restrict__ ipb,
    const short* __restrict__ opwb, const float* __restrict__ opb,
    const float* __restrict__ l1g, const float* __restrict__ l1b)
{
    __shared__ short Sb[48 * 128] __attribute__((aligned(16)));
    __shared__ char  U[38912]     __attribute__((aligned(16)));
    __shared__ float scf[36 * 40];
    short* Qb = (short*)U;               // 48x64
    short* Kb = (short*)(U + 6144);      // 48x64
    short* Vt = (short*)(U + 12288);     // 64x64 [d][seq]
    short* Pb = (short*)(U + 20480);     // 48x64
    short* Hb = (short*)(U + 26624);     // 48x128

    const int tid  = threadIdx.x;
    const int wid  = tid >> 6;
    const int lane = tid & 63;
    const int lr   = lane & 15;
    const int lg   = lane >> 4;
    const int kbse = lg * 16;

    float* sg = sbuf + (size_t)blockIdx.x * 4608;
    const f32x4 fzero = {0.f, 0.f, 0.f, 0.f};

    // ---- init (NOTE: contraction-dim pads MUST be zeroed — 0*garbage=NaN
    //      inside MFMA; A-row pads zeroed for safety too) ----
    for (int idx = tid; idx < 4608; idx += 256) {
        int r = idx >> 7, c = idx & 127;
        stswz(Sb, r, c, 256, f2bf(sg[idx]));
    }
    for (int idx = tid; idx < 1536; idx += 256)                 // Sb pad rows 36..47
        stswz(Sb, 36 + (idx >> 7), idx & 127, 256, 0);
    for (int idx = tid; idx < 1024; idx += 256)                 // Vt seq cols 48..63
        stswz(Vt, idx >> 4, 48 + (idx & 15), 128, 0);
    for (int idx = tid; idx < 768; idx += 256)                  // Pb pad rows 36..47
        stswz(Pb, 36 + (idx >> 6), idx & 63, 128, 0);
    __syncthreads();

    for (int h = 0; h < 2; ++h) {
        {   // q,k,v projections
            f32x4 acc[3][3];
            #pragma unroll
            for (int a = 0; a < 3; ++a)
                #pragma unroll
                for (int m = 0; m < 3; ++m) acc[a][m] = fzero;
            const int wrow0 = h * 64 + wid * 16 + lr;
            #pragma unroll
            for (int ks = 0; ks < 4; ++ks) {
                bf16x8 a0 = ldfrag(Sb,      lr, ks * 64 + kbse, 256);
                bf16x8 a1 = ldfrag(Sb, 16 + lr, ks * 64 + kbse, 256);
                bf16x8 a2 = ldfrag(Sb, 32 + lr, ks * 64 + kbse, 256);
                #pragma unroll
                for (int mat = 0; mat < 3; ++mat) {
                    bf16x8 bf = ldfragG(ipwb, mat * 128 + wrow0, ks * 64 + kbse, 256);
                    acc[mat][0] = mfma16(a0, bf, acc[mat][0]);
                    acc[mat][1] = mfma16(a1, bf, acc[mat][1]);
                    acc[mat][2] = mfma16(a2, bf, acc[mat][2]);
                }
            }
            int col = wid * 16 + lr;
            #pragma unroll
            for (int mat = 0; mat < 3; ++mat) {
                float bias = ipb[mat * 128 + h * 64 + col];
                #pragma unroll
                for (int mt = 0; mt < 3; ++mt) {
                    f32x4 c4 = acc[mat][mt];
                    if (mat == 0) {
                        #pragma unroll
                        for (int j = 0; j < 4; ++j)
                            stswz(Qb, mt * 16 + lg * 4 + j, col, 128, f2bf(c4[j] + bias));
                    } else if (mat == 1) {
                        #pragma unroll
                        for (int j = 0; j < 4; ++j)
                            stswz(Kb, mt * 16 + lg * 4 + j, col, 128, f2bf(c4[j] + bias));
                    } else {
                        // V transposed; seq>=36 forced to 0 (contraction dim of PV)
                        int rbase = mt * 16 + lg * 4;
                        short4 s4;
                        s4.x = f2bf(rbase + 0 < 36 ? c4[0] + bias : 0.f);
                        s4.y = f2bf(rbase + 1 < 36 ? c4[1] + bias : 0.f);
                        s4.z = f2bf(rbase + 2 < 36 ? c4[2] + bias : 0.f);
                        s4.w = f2bf(rbase + 3 < 36 ? c4[3] + bias : 0.f);
                        int byte = col * 128 + rbase * 2;
                        byte ^= (col & 7) << 4;
                        *(short4*)((char*)Vt + byte) = s4;
                    }
                }
            }
        }
        __syncthreads();

        // scores
        for (int t = wid; t < 9; t += 4) {
            int mt = t / 3, nt = t - mt * 3;
            f32x4 acc = fzero;
            #pragma unroll
            for (int ks = 0; ks < 2; ++ks) {
                bf16x8 a = ldfrag(Qb, mt * 16 + lr, ks * 64 + kbse, 128);
                bf16x8 b = ldfrag(Kb, nt * 16 + lr, ks * 64 + kbse, 128);
                acc = mfma16(a, b, acc);
            }
            int col = nt * 16 + lr;
            if (col < 36) {
                #pragma unroll
                for (int j = 0; j < 4; ++j) {
                    int r = mt * 16 + lg * 4 + j;
                    if (r < 36) scf[r * 40 + col] = acc[j] * 0.125f;
                }
            }
        }
        __syncthreads();

        // softmax (4 lanes per row)
        {
            int g = tid >> 2, e = tid & 3;
            if (g < 36) {
                float v[9];
                float mx = -1e30f;
                #pragma unroll
                for (int i = 0; i < 9; ++i) { v[i] = scf[g * 40 + e * 9 + i]; mx = fmaxf(mx, v[i]); }
                mx = fmaxf(mx, __shfl_xor(mx, 1));
                mx = fmaxf(mx, __shfl_xor(mx, 2));
                float ssum = 0.f;
                #pragma unroll
                for (int i = 0; i < 9; ++i) { v[i] = __expf(v[i] - mx); ssum += v[i]; }
                ssum += __shfl_xor(ssum, 1);
                ssum += __shfl_xor(ssum, 2);
                float inv = 1.f / ssum;
                #pragma unroll
                for (int i = 0; i < 9; ++i)
                    stswz(Pb, g, e * 9 + i, 128, f2bf(v[i] * inv));
                #pragma unroll
                for (int i = 0; i < 7; ++i)
                    stswz(Pb, g, 36 + e * 7 + i, 128, 0);
            }
        }
        __syncthreads();

        // o = P @ V
        {
            f32x4 oacc[3] = {fzero, fzero, fzero};
            #pragma unroll
            for (int ks = 0; ks < 2; ++ks) {
                bf16x8 b = ldfrag(Vt, wid * 16 + lr, ks * 64 + kbse, 128);
                #pragma unroll
                for (int mt = 0; mt < 3; ++mt) {
                    bf16x8 a = ldfrag(Pb, mt * 16 + lr, ks * 64 + kbse, 128);
                    oacc[mt] = mfma16(a, b, oacc[mt]);
                }
            }
            int col = h * 64 + wid * 16 + lr;
            #pragma unroll
            for (int mt = 0; mt < 3; ++mt)
                #pragma unroll
                for (int j = 0; j < 4; ++j)
                    stswz(Hb, mt * 16 + lg * 4 + j, col, 256, f2bf(oacc[mt][j]));
        }
        __syncthreads();
    }

    // out-proj + residual (from global) + in-register LN1
    float z[3][2][4];
    {
        f32x4 pacc[3][2];
        #pragma unroll
        for (int m = 0; m < 3; ++m) { pacc[m][0] = fzero; pacc[m][1] = fzero; }
        #pragma unroll
        for (int ks = 0; ks < 4; ++ks) {
            bf16x8 a0 = ldfrag(Hb,      lr, ks * 64 + kbse, 256);
            bf16x8 a1 = ldfrag(Hb, 16 + lr, ks * 64 + kbse, 256);
            bf16x8 a2 = ldfrag(Hb, 32 + lr, ks * 64 + kbse, 256);
            #pragma unroll
            for (int t = 0; t < 2; ++t) {
                bf16x8 b = ldfragG(opwb, (wid * 2 + t) * 16 + lr, ks * 64 + kbse, 256);
                pacc[0][t] = mfma16(a0, b, pacc[0][t]);
                pacc[1][t] = mfma16(a1, b, pacc[1][t]);
                pacc[2][t] = mfma16(a2, b, pacc[2][t]);
            }
        }
        #pragma unroll
        for (int t = 0; t < 2; ++t) {
            int col = (wid * 2 + t) * 16 + lr;
            float bias = opb[col];
            #pragma unroll
            for (int mt = 0; mt < 3; ++mt)
                #pragma unroll
                for (int j = 0; j < 4; ++j) {
                    int r = mt * 16 + lg * 4 + j;
                    z[mt][t][j] = (r < 36) ? pacc[mt][t][j] + bias + sg[r * 128 + col] : 0.f;
                }
        }
    }
    // LN1 partials -> scf scratch
    {
        float* part = scf;
        #pragma unroll
        for (int mt = 0; mt < 3; ++mt)
            #pragma unroll
            for (int j = 0; j < 4; ++j) {
                int r = mt * 16 + lg * 4 + j;
                float s  = z[mt][0][j] + z[mt][1][j];
                float ss = z[mt][0][j] * z[mt][0][j] + z[mt][1][j] * z[mt][1][j];
                s  += __shfl_xor(s, 1);  s  += __shfl_xor(s, 2);
                s  += __shfl_xor(s, 4);  s  += __shfl_xor(s, 8);
                ss += __shfl_xor(ss, 1); ss += __shfl_xor(ss, 2);
                ss += __shfl_xor(ss, 4); ss += __shfl_xor(ss, 8);
                if (lr == 0 && r < 36) { part[r * 8 + wid] = s; part[r * 8 + 4 + wid] = ss; }
            }
    }
    __syncthreads();
    {
        const float* part = scf;
        #pragma unroll
        for (int mt = 0; mt < 3; ++mt)
            #pragma unroll
            for (int j = 0; j < 4; ++j) {
                int r = mt * 16 + lg * 4 + j;
                if (r < 36) {
                    float s  = part[r * 8 + 0] + part[r * 8 + 1] + part[r * 8 + 2] + part[r * 8 + 3];
                    float ss = part[r * 8 + 4] + part[r * 8 + 5] + part[r * 8 + 6] + part[r * 8 + 7];
                    float mean = s * (1.f / 128.f);
                    float rstd = rsqrtf(ss * (1.f / 128.f) - mean * mean + EPSV);
                    #pragma unroll
                    for (int t = 0; t < 2; ++t) {
                        int col = (wid * 2 + t) * 16 + lr;
                        float v = (z[mt][t][j] - mean) * rstd * l1g[col] + l1b[col];
                        sg[r * 128 + col] = v;
                    }
                }
            }
    }
}

// ---------------------------------------------------------------------------
// Batched fused FFN + LN2: M=36864 rows, 64 rows/block, 4 waves split N.
// ---------------------------------------------------------------------------
__global__ __launch_bounds__(256, 3) void ffn_mfma(
    float* __restrict__ sres,
    const short* __restrict__ fw1b, const float* __restrict__ fb1,
    const short* __restrict__ fw2b, const float* __restrict__ fb2,
    const float* __restrict__ l2g, const float* __restrict__ l2b)
{
    __shared__ short Ab[64 * 128]    __attribute__((aligned(16)));
    __shared__ short Hp[2][64 * 128] __attribute__((aligned(16)));
    __shared__ float part[2][64][4];

    const int tid  = threadIdx.x;
    const int wid  = tid >> 6;
    const int lane = tid & 63;
    const int lr   = lane & 15;
    const int lg   = lane >> 4;
    const int kbse = lg * 16;
    const size_t row0 = (size_t)blockIdx.x * 64;
    const f32x4 fzero = {0.f, 0.f, 0.f, 0.f};

    // stage A: f32 -> bf16 swizzled
    for (int u = tid; u < 2048; u += 256) {
        int r = u >> 5, c4 = (u & 31) * 4;
        float4 v = *(const float4*)(sres + (row0 + r) * 128 + c4);
        short4 s;
        s.x = f2bf(v.x); s.y = f2bf(v.y); s.z = f2bf(v.z); s.w = f2bf(v.w);
        int byte = r * 256 + ((c4 * 2) ^ ((r & 7) << 4));
        *(short4*)((char*)Ab + byte) = s;
    }
    __syncthreads();

    const int n0 = wid * 32;
    f32x4 facc[4][2];
    #pragma unroll
    for (int m = 0; m < 4; ++m) { facc[m][0] = fzero; facc[m][1] = fzero; }

    bf16x8 p1[8], p2[8];
    #pragma unroll
    for (int t = 0; t < 2; ++t)
        #pragma unroll
        for (int ks = 0; ks < 4; ++ks)
            p1[t * 4 + ks] = ldfragG(fw1b, n0 + t * 16 + lr, ks * 64 + kbse, 256);

    #pragma unroll 1
    for (int q = 0; q < 16; ++q) {
        short* Hb = Hp[q & 1];
        #pragma unroll
        for (int t = 0; t < 2; ++t)
            #pragma unroll
            for (int ks = 0; ks < 4; ++ks)
                p2[t * 4 + ks] = ldfragG(fw2b, n0 + t * 16 + lr,
                                         q * 256 + ks * 64 + kbse, 4096);
        float b1a = fb1[q * 128 + n0 + lr];
        float b1b = fb1[q * 128 + n0 + 16 + lr];

        f32x4 hacc[4][2];
        #pragma unroll
        for (int m = 0; m < 4; ++m) { hacc[m][0] = fzero; hacc[m][1] = fzero; }
        #pragma unroll
        for (int ks = 0; ks < 4; ++ks) {
            bf16x8 a0 = ldfrag(Ab,      lr, ks * 64 + kbse, 256);
            bf16x8 a1 = ldfrag(Ab, 16 + lr, ks * 64 + kbse, 256);
            bf16x8 a2 = ldfrag(Ab, 32 + lr, ks * 64 + kbse, 256);
            bf16x8 a3 = ldfrag(Ab, 48 + lr, ks * 64 + kbse, 256);
            #pragma unroll
            for (int t = 0; t < 2; ++t) {
                hacc[0][t] = mfma16(a0, p1[t * 4 + ks], hacc[0][t]);
                hacc[1][t] = mfma16(a1, p1[t * 4 + ks], hacc[1][t]);
                hacc[2][t] = mfma16(a2, p1[t * 4 + ks], hacc[2][t]);
                hacc[3][t] = mfma16(a3, p1[t * 4 + ks], hacc[3][t]);
            }
        }
        #pragma unroll
        for (int t = 0; t < 2; ++t) {
            int col = n0 + t * 16 + lr;
            float bias = t ? b1b : b1a;
            #pragma unroll
            for (int mt = 0; mt < 4; ++mt)
                #pragma unroll
                for (int j = 0; j < 4; ++j)
                    stswz(Hb, mt * 16 + lg * 4 + j, col, 256,
                          f2bf(fmaxf(hacc[mt][t][j] + bias, 0.f)));
        }
        __syncthreads();
        if (q < 15) {
            #pragma unroll
            for (int t = 0; t < 2; ++t)
                #pragma unroll
                for (int ks = 0; ks < 4; ++ks)
                    p1[t * 4 + ks] = ldfragG(fw1b,
                        (q + 1) * 128 + n0 + t * 16 + lr, ks * 64 + kbse, 256);
        }
        #pragma unroll
        for (int ks = 0; ks < 4; ++ks) {
            bf16x8 a0 = ldfrag(Hb,      lr, ks * 64 + kbse, 256);
            bf16x8 a1 = ldfrag(Hb, 16 + lr, ks * 64 + kbse, 256);
            bf16x8 a2 = ldfrag(Hb, 32 + lr, ks * 64 + kbse, 256);
            bf16x8 a3 = ldfrag(Hb, 48 + lr, ks * 64 + kbse, 256);
            #pragma unroll
            for (int t = 0; t < 2; ++t) {
                facc[0][t] = mfma16(a0, p2[t * 4 + ks], facc[0][t]);
                facc[1][t] = mfma16(a1, p2[t * 4 + ks], facc[1][t]);
                facc[2][t] = mfma16(a2, p2[t * 4 + ks], facc[2][t]);
                facc[3][t] = mfma16(a3, p2[t * 4 + ks], facc[3][t]);
            }
        }
    }

    // epilogue: + b2 + residual, LN2
    float z[4][2][4];
    #pragma unroll
    for (int t = 0; t < 2; ++t) {
        int col = n0 + t * 16 + lr;
        float fb2v = fb2[col];
        #pragma unroll
        for (int mt = 0; mt < 4; ++mt)
            #pragma unroll
            for (int j = 0; j < 4; ++j) {
                int r = mt * 16 + lg * 4 + j;
                z[mt][t][j] = facc[mt][t][j] + fb2v + sres[(row0 + r) * 128 + col];
            }
    }
    #pragma unroll
    for (int mt = 0; mt < 4; ++mt)
        #pragma unroll
        for (int j = 0; j < 4; ++j) {
            float s  = z[mt][0][j] + z[mt][1][j];
            float ss = z[mt][0][j] * z[mt][0][j] + z[mt][1][j] * z[mt][1][j];
            s  += __shfl_xor(s, 1);  s  += __shfl_xor(s, 2);
            s  += __shfl_xor(s, 4);  s  += __shfl_xor(s, 8);
            ss += __shfl_xor(ss, 1); ss += __shfl_xor(ss, 2);
            ss += __shfl_xor(ss, 4); ss += __shfl_xor(ss, 8);
            if (lr == 0) {
                int r = mt * 16 + lg * 4 + j;
                part[0][r][wid] = s;
                part[1][r][wid] = ss;
            }
        }
    __syncthreads();
    {
        float lg2[2], lb2[2];
        #pragma unroll
        for (int t = 0; t < 2; ++t) {
            int col = n0 + t * 16 + lr;
            lg2[t] = l2g[col];
            lb2[t] = l2b[col];
        }
        #pragma unroll
        for (int mt = 0; mt < 4; ++mt)
            #pragma unroll
            for (int j = 0; j < 4; ++j) {
                int r = mt * 16 + lg * 4 + j;
                float s  = part[0][r][0] + part[0][r][1] + part[0][r][2] + part[0][r][3];
                float ss = part[1][r][0] + part[1][r][1] + part[1][r][2] + part[1][r][3];
                float mean = s * (1.f / 128.f);
                float rstd = rsqrtf(ss * (1.f / 128.f) - mean * mean + EPSV);
                #pragma unroll
                for (int t = 0; t < 2; ++t) {
                    int col = n0 + t * 16 + lr;
                    sres[(row0 + r) * 128 + col] =
                        (z[mt][t][j] - mean) * rstd * lg2[t] + lb2[t];
                }
            }
    }
}

// ---------------------------------------------------------------------------
// pool + head (unchanged)
// ---------------------------------------------------------------------------
__global__ __launch_bounds__(128) void pool_head(
    const float* __restrict__ sbuf, const float* __restrict__ xgcn,
    const float* __restrict__ aww, const float* __restrict__ awb,
    const float* __restrict__ fcw, const float* __restrict__ fcb,
    float* __restrict__ out)
{
    __shared__ float sl[36][128];
    __shared__ float zz[36];
    __shared__ float p[128];
    int tid = threadIdx.x;
    int b = blockIdx.x;
    const float* sg = sbuf + (size_t)b * 4608;
    const float* gg = xgcn + (size_t)b * 4608;
    for (int idx = tid; idx < 4608; idx += 128)
        sl[0][idx] = sg[idx] + gg[idx];
    __syncthreads();
    if (tid < 36) {
        float acc = awb[0];
        #pragma unroll
        for (int j = 0; j < 128; j += 4) {
            float4 s4 = *(const float4*)&sl[tid][j];
            float4 w4 = *(const float4*)(aww + j);
            acc += s4.x * w4.x + s4.y * w4.y + s4.z * w4.z + s4.w * w4.w;
        }
        zz[tid] = acc;
    }
    __syncthreads();
    if (tid == 0) {
        float m = -1e30f;
        for (int k = 0; k < 36; ++k) m = fmaxf(m, zz[k]);
        float ssum = 0.f;
        for (int k = 0; k < 36; ++k) ssum += __expf(zz[k] - m);
        float inv = 1.f / ssum;
        for (int k = 0; k < 36; ++k) zz[k] = __expf(zz[k] - m) * inv;
    }
    __syncthreads();
    {
        float acc = 0.f;
        for (int l = 0; l < 36; ++l) acc += sl[l][tid] * zz[l];
        p[tid] = acc;
    }
    __syncthreads();
    if (tid == 0) {
        float acc = fcb[0];
        for (int dd = 0; dd < 128; ++dd) acc += p[dd] * fcw[dd];
        out[b] = acc >= 0.f ? acc : 0.1f * acc;
    }
}

// ---------------------------------------------------------------------------
extern "C" void kernel_launch(void* const* d_in, const int* in_sizes, int n_in,
                              void* d_out, int out_size, void* d_ws, size_t ws_size,
                              hipStream_t stream)
{
    const float* x   = (const float*)d_in[0];
    const float* Wg1 = (const float*)d_in[1];
    const float* bg1 = (const float*)d_in[2];
    const float* Wg2 = (const float*)d_in[3];
    const float* bg2 = (const float*)d_in[4];
    const float* c1w = (const float*)d_in[5];
    const float* c1b = (const float*)d_in[6];
    const float* c2w = (const float*)d_in[7];
    const float* c2b = (const float*)d_in[8];
    const float* bng = (const float*)d_in[9];
    const float* bnb = (const float*)d_in[10];
    const float* bnm = (const float*)d_in[11];
    const float* bnv = (const float*)d_in[12];
    const float* ipw = (const float*)d_in[13];
    const float* ipb = (const float*)d_in[14];
    const float* opw = (const float*)d_in[15];
    const float* opb = (const float*)d_in[16];
    const float* l1g = (const float*)d_in[17];
    const float* l1b = (const float*)d_in[18];
    const float* l2g = (const float*)d_in[19];
    const float* l2b = (const float*)d_in[20];
    const float* fw1 = (const float*)d_in[21];
    const float* fb1 = (const float*)d_in[22];
    const float* fw2 = (const float*)d_in[23];
    const float* fb2 = (const float*)d_in[24];
    const float* aww = (const float*)d_in[25];
    const float* awb = (const float*)d_in[26];
    const float* fcw = (const float*)d_in[27];
    const float* fcb = (const float*)d_in[28];
    float* out = (float*)d_out;

    float* sbuf = (float*)d_ws;                       // 1024*36*128 f32
    float* xgcn = sbuf + (size_t)1024 * 36 * 128;     // 1024*36*128 f32
    short* wb   = (short*)(xgcn + (size_t)1024 * 36 * 128);
    short* ipwb = wb;                  // 2*384*128
    short* opwb = wb + 98304;          // 2*128*128
    short* fw1b = wb + 131072;         // 2*2048*128
    short* fw2b = wb + 655360;         // 2*128*2048

    cvt_all<<<1152, 256, 0, stream>>>(ipw, opw, fw1, fw2, wb);
    gcn_all<<<18433, 256, 0, stream>>>(x, Wg1, bg1, Wg2, bg2, xgcn);
    conv_branch<<<1024, 256, 0, stream>>>(x, c1w, c1b, c2w, c2b,
                                          bng, bnb, bnm, bnv, sbuf);
    for (int i = 0; i < 2; ++i) {
        attn_mfma<<<1024, 256, 0, stream>>>(sbuf,
            ipwb + (size_t)i * 49152, ipb + (size_t)i * 384,
            opwb + (size_t)i * 16384, opb + (size_t)i * 128,
            l1g + (size_t)i * 128, l1b + (size_t)i * 128);
        ffn_mfma<<<576, 256, 0, stream>>>(sbuf,
            fw1b + (size_t)i * 262144, fb1 + (size_t)i * 2048,
            fw2b + (size_t)i * 262144, fb2 + (size_t)i * 128,
            l2g + (size_t)i * 128, l2b + (size_t)i * 128);
    }
    pool_head<<<1024, 128, 0, stream>>>(sbuf, xgcn, aww, awb, fcw, fcb, out);
}

// Round 7
// 461.726 us; speedup vs baseline: 1.0013x; 1.0013x over previous
//
#include <hip/hip_runtime.h>
#include <math.h>

#define EPSV   1e-5f

typedef __attribute__((ext_vector_type(8))) short bf16x8;
typedef __attribute__((ext_vector_type(4))) float f32x4;

__device__ __forceinline__ short f2bf(float f){
    unsigned u = __float_as_uint(f);
    u += 0x7fffu + ((u >> 16) & 1u);
    return (short)(u >> 16);
}
__device__ __forceinline__ f32x4 mfma16(bf16x8 a, bf16x8 b, f32x4 c){
    return __builtin_amdgcn_mfma_f32_16x16x32_bf16(a, b, c, 0, 0, 0);
}
__device__ __forceinline__ bf16x8 ldfrag(const short* base, int row, int kbyte, int rowBytes){
    int byte = row * rowBytes + kbyte;
    byte ^= (row & 7) << 4;
    return *(const bf16x8*)((const char*)base + byte);
}
__device__ __forceinline__ bf16x8 ldfragG(const short* base, int row, int kbyte, int rowBytes){
    return *(const bf16x8*)((const char*)base + (size_t)row * rowBytes + kbyte);
}
__device__ __forceinline__ void stswz(short* base, int row, int col, int rowBytes, short v){
    int byte = row * rowBytes + col * 2;
    byte ^= (row & 7) << 4;
    *(short*)((char*)base + byte) = v;
}

// ---------------------------------------------------------------------------
// one-shot fp32 -> bf16 weight conversion.
// fw2 is written PERMUTED (fw2p) to match the in-register FFN2 k-slot map:
//   fw2p[(((grp*128 + c)*4 + lg)*8 + s)] = W2[c][grp*32 + (s>>2)*16 + lg*4 + (s&3)]
// (grp = 32-neuron group = q*4+wid; per-layer stride 262144 elements)
// ---------------------------------------------------------------------------
__global__ __launch_bounds__(256) void cvt_all(
    const float* __restrict__ ipw, const float* __restrict__ opw,
    const float* __restrict__ fw1, const float* __restrict__ fw2,
    short* __restrict__ dst)
{
    int i = (blockIdx.x * 256 + threadIdx.x) * 4;
    if (i >= 1179648) return;
    const float* src; int off;
    if (i < 98304)       { src = ipw; off = i; }
    else if (i < 131072) { src = opw; off = i - 98304; }
    else if (i < 655360) { src = fw1; off = i - 131072; }
    else {
        // permuted fw2: decode dst index -> src index
        int o  = i - 655360;
        int L  = o >> 18;              // layer
        int oo = o & 262143;
        int s0 = oo & 7;               // 0 or 4 (i % 8 in slot space)
        int lg = (oo >> 3) & 3;
        int c  = (oo >> 5) & 127;
        int grp = oo >> 12;
        int n  = grp * 32 + ((s0 >> 2) << 4) + lg * 4;   // 4 consecutive src elems
        src = fw2; off = L * 262144 + c * 2048 + n;
        float4 v = *(const float4*)(src + off);
        short4 s;
        s.x = f2bf(v.x); s.y = f2bf(v.y); s.z = f2bf(v.z); s.w = f2bf(v.w);
        *(short4*)(dst + i) = s;
        return;
    }
    float4 v = *(const float4*)(src + off);
    short4 s;
    s.x = f2bf(v.x); s.y = f2bf(v.y); s.z = f2bf(v.z); s.w = f2bf(v.w);
    *(short4*)(dst + i) = s;
}

// ---------------------------------------------------------------------------
// GCN branch (gcn_small folded in as the last block)
// ---------------------------------------------------------------------------
__global__ __launch_bounds__(256) void gcn_all(
    const float* __restrict__ x,
    const float* __restrict__ Wg1, const float* __restrict__ bg1,
    const float* __restrict__ Wg2, const float* __restrict__ bg2,
    float* __restrict__ xgcn)
{
    int tid = threadIdx.x;
    if (blockIdx.x == 18432) {
        __shared__ float xgm[9];
        __shared__ float h1s[64];
        if (tid < 9) {
            float s = 0.f;
            for (int r = 0; r < 9; ++r) {
                const float* xp = x + (r * 9 + tid) * 7;
                #pragma unroll
                for (int f = 0; f < 7; ++f) s += xp[f];
            }
            xgm[tid] = s * (1.f / 63.f);
        }
        __syncthreads();
        if (tid < 64) {
            float acc = bg1[tid];
            #pragma unroll
            for (int j = 0; j < 9; ++j) acc += xgm[j] * Wg1[j * 64 + tid];
            h1s[tid] = fmaxf(acc, 0.f);
        }
        __syncthreads();
        if (tid < 128) {
            float acc = bg2[tid];
            #pragma unroll 8
            for (int c = 0; c < 64; ++c) acc += h1s[c] * Wg2[c * 128 + tid];
            float v = fmaxf(acc, 0.f);
            for (int r = 0; r < 9; ++r) xgcn[r * 128 + tid] = v;
        }
        return;
    }

    __shared__ float xg[2][9];
    __shared__ float h1[2][64];
    int ri = tid >> 7;
    int tr = tid & 127;
    int row = blockIdx.x * 2 + ri;

    if (tr < 9) {
        const float* xp = x + (row * 9 + tr) * 7;
        float s = 0.f;
        #pragma unroll
        for (int f = 0; f < 7; ++f) s += xp[f];
        xg[ri][tr] = s * (1.f / 7.f);
    }
    __syncthreads();
    if (tr < 64) {
        float acc = bg1[tr];
        #pragma unroll
        for (int j = 0; j < 9; ++j) acc += xg[ri][j] * Wg1[j * 64 + tr];
        h1[ri][tr] = fmaxf(acc, 0.f);
    }
    __syncthreads();
    if (row >= 9) {
        float acc = bg2[tr];
        #pragma unroll 8
        for (int c = 0; c < 64; ++c) acc += h1[ri][c] * Wg2[c * 128 + tr];
        xgcn[row * 128 + tr] = fmaxf(acc, 0.f);
    }
}

// ---------------------------------------------------------------------------
// Conv branch (unchanged)
// ---------------------------------------------------------------------------
__global__ __launch_bounds__(256) void conv_branch(
    const float* __restrict__ x,
    const float* __restrict__ w1, const float* __restrict__ cb1,
    const float* __restrict__ w2, const float* __restrict__ cb2,
    const float* __restrict__ bng, const float* __restrict__ bnb,
    const float* __restrict__ bnm, const float* __restrict__ bnv,
    float* __restrict__ sbuf)
{
    __shared__ float xm[7 * 40];
    __shared__ float w1s[64 * 35];
    __shared__ float o1[64 * 38];
    int tid = threadIdx.x;
    int b = blockIdx.x;

    for (int idx = tid; idx < 7 * 40; idx += 256) xm[idx] = 0.f;
    for (int idx = tid; idx < 64 * 38; idx += 256) o1[idx] = 0.f;
    for (int idx = tid; idx < 2240; idx += 256) w1s[idx] = w1[idx];
    __syncthreads();

    const float* xb = x + (size_t)b * 2268;
    for (int idx = tid; idx < 252; idx += 256) {
        int f = idx / 36, l = idx - f * 36;
        float s = 0.f;
        #pragma unroll
        for (int n = 0; n < 9; ++n) s += xb[n * 252 + idx];
        xm[f * 40 + l + 2] = s * (1.f / 9.f);
    }
    __syncthreads();

    {
        int o = tid & 63, lh = tid >> 6;
        int l0 = lh * 9;
        float acc[9];
        float bias = cb1[o];
        #pragma unroll
        for (int r = 0; r < 9; ++r) acc[r] = bias;
        #pragma unroll
        for (int i = 0; i < 7; ++i) {
            #pragma unroll
            for (int k = 0; k < 5; ++k) {
                float w = w1s[o * 35 + i * 5 + k];
                const float* xrow = &xm[i * 40 + l0 + k];
                #pragma unroll
                for (int r = 0; r < 9; ++r) acc[r] += w * xrow[r];
            }
        }
        #pragma unroll
        for (int r = 0; r < 9; ++r) o1[o * 38 + l0 + r + 1] = acc[r];
    }
    __syncthreads();

    {
        int c = tid & 127, lh = tid >> 7;
        int l0 = lh * 18;
        float acc[18];
        #pragma unroll
        for (int r = 0; r < 18; ++r) acc[r] = 0.f;
        const float* w2c = w2 + c * 192;
        for (int i = 0; i < 64; ++i) {
            float wa = w2c[i * 3 + 0], wb = w2c[i * 3 + 1], wc = w2c[i * 3 + 2];
            const float* orow = &o1[i * 38 + l0];
            #pragma unroll
            for (int r = 0; r < 18; ++r)
                acc[r] += wa * orow[r] + wb * orow[r + 1] + wc * orow[r + 2];
        }
        float scale = bng[c] * rsqrtf(bnv[c] + EPSV);
        float shift = bnb[c] - bnm[c] * scale;
        float bias  = cb2[c];
        float* sb = sbuf + ((size_t)b * 36 + l0) * 128 + c;
        #pragma unroll
        for (int r = 0; r < 18; ++r)
            sb[r * 128] = (acc[r] + bias) * scale + shift;
    }
}

// ---------------------------------------------------------------------------
// Attention + out-proj + residual + LN1 (unchanged from round 6)
// ---------------------------------------------------------------------------
__global__ __launch_bounds__(256, 2) void attn_mfma(
    float* __restrict__ sbuf,
    const short* __restrict__ ipwb, const float* __restrict__ ipb,
    const short* __restrict__ opwb, const float* __restrict__ opb,
    const float* __restrict__ l1g, const float* __restrict__ l1b)
{
    __shared__ short Sb[48 * 128] __attribute__((aligned(16)));
    __shared__ char  U[38912]     __attribute__((aligned(16)));
    __shared__ float scf[36 * 40];
    short* Qb = (short*)U;               // 48x64
    short* Kb = (short*)(U + 6144);      // 48x64
    short* Vt = (short*)(U + 12288);     // 64x64 [d][seq]
    short* Pb = (short*)(U + 20480);     // 48x64
    short* Hb = (short*)(U + 26624);     // 48x128

    const int tid  = threadIdx.x;
    const int wid  = tid >> 6;
    const int lane = tid & 63;
    const int lr   = lane & 15;
    const int lg   = lane >> 4;
    const int kbse = lg * 16;

    float* sg = sbuf + (size_t)blockIdx.x * 4608;
    const f32x4 fzero = {0.f, 0.f, 0.f, 0.f};

    for (int idx = tid; idx < 4608; idx += 256) {
        int r = idx >> 7, c = idx & 127;
        stswz(Sb, r, c, 256, f2bf(sg[idx]));
    }
    for (int idx = tid; idx < 1536; idx += 256)                 // Sb pad rows 36..47
        stswz(Sb, 36 + (idx >> 7), idx & 127, 256, 0);
    for (int idx = tid; idx < 1024; idx += 256)                 // Vt seq cols 48..63
        stswz(Vt, idx >> 4, 48 + (idx & 15), 128, 0);
    for (int idx = tid; idx < 768; idx += 256)                  // Pb pad rows 36..47
        stswz(Pb, 36 + (idx >> 6), idx & 63, 128, 0);
    __syncthreads();

    for (int h = 0; h < 2; ++h) {
        {   // q,k,v projections
            f32x4 acc[3][3];
            #pragma unroll
            for (int a = 0; a < 3; ++a)
                #pragma unroll
                for (int m = 0; m < 3; ++m) acc[a][m] = fzero;
            const int wrow0 = h * 64 + wid * 16 + lr;
            #pragma unroll
            for (int ks = 0; ks < 4; ++ks) {
                bf16x8 a0 = ldfrag(Sb,      lr, ks * 64 + kbse, 256);
                bf16x8 a1 = ldfrag(Sb, 16 + lr, ks * 64 + kbse, 256);
                bf16x8 a2 = ldfrag(Sb, 32 + lr, ks * 64 + kbse, 256);
                #pragma unroll
                for (int mat = 0; mat < 3; ++mat) {
                    bf16x8 bf = ldfragG(ipwb, mat * 128 + wrow0, ks * 64 + kbse, 256);
                    acc[mat][0] = mfma16(a0, bf, acc[mat][0]);
                    acc[mat][1] = mfma16(a1, bf, acc[mat][1]);
                    acc[mat][2] = mfma16(a2, bf, acc[mat][2]);
                }
            }
            int col = wid * 16 + lr;
            #pragma unroll
            for (int mat = 0; mat < 3; ++mat) {
                float bias = ipb[mat * 128 + h * 64 + col];
                #pragma unroll
                for (int mt = 0; mt < 3; ++mt) {
                    f32x4 c4 = acc[mat][mt];
                    if (mat == 0) {
                        #pragma unroll
                        for (int j = 0; j < 4; ++j)
                            stswz(Qb, mt * 16 + lg * 4 + j, col, 128, f2bf(c4[j] + bias));
                    } else if (mat == 1) {
                        #pragma unroll
                        for (int j = 0; j < 4; ++j)
                            stswz(Kb, mt * 16 + lg * 4 + j, col, 128, f2bf(c4[j] + bias));
                    } else {
                        int rbase = mt * 16 + lg * 4;
                        short4 s4;
                        s4.x = f2bf(rbase + 0 < 36 ? c4[0] + bias : 0.f);
                        s4.y = f2bf(rbase + 1 < 36 ? c4[1] + bias : 0.f);
                        s4.z = f2bf(rbase + 2 < 36 ? c4[2] + bias : 0.f);
                        s4.w = f2bf(rbase + 3 < 36 ? c4[3] + bias : 0.f);
                        int byte = col * 128 + rbase * 2;
                        byte ^= (col & 7) << 4;
                        *(short4*)((char*)Vt + byte) = s4;
                    }
                }
            }
        }
        __syncthreads();

        // scores
        for (int t = wid; t < 9; t += 4) {
            int mt = t / 3, nt = t - mt * 3;
            f32x4 acc = fzero;
            #pragma unroll
            for (int ks = 0; ks < 2; ++ks) {
                bf16x8 a = ldfrag(Qb, mt * 16 + lr, ks * 64 + kbse, 128);
                bf16x8 b = ldfrag(Kb, nt * 16 + lr, ks * 64 + kbse, 128);
                acc = mfma16(a, b, acc);
            }
            int col = nt * 16 + lr;
            if (col < 36) {
                #pragma unroll
                for (int j = 0; j < 4; ++j) {
                    int r = mt * 16 + lg * 4 + j;
                    if (r < 36) scf[r * 40 + col] = acc[j] * 0.125f;
                }
            }
        }
        __syncthreads();

        // softmax (4 lanes per row)
        {
            int g = tid >> 2, e = tid & 3;
            if (g < 36) {
                float v[9];
                float mx = -1e30f;
                #pragma unroll
                for (int i = 0; i < 9; ++i) { v[i] = scf[g * 40 + e * 9 + i]; mx = fmaxf(mx, v[i]); }
                mx = fmaxf(mx, __shfl_xor(mx, 1));
                mx = fmaxf(mx, __shfl_xor(mx, 2));
                float ssum = 0.f;
                #pragma unroll
                for (int i = 0; i < 9; ++i) { v[i] = __expf(v[i] - mx); ssum += v[i]; }
                ssum += __shfl_xor(ssum, 1);
                ssum += __shfl_xor(ssum, 2);
                float inv = 1.f / ssum;
                #pragma unroll
                for (int i = 0; i < 9; ++i)
                    stswz(Pb, g, e * 9 + i, 128, f2bf(v[i] * inv));
                #pragma unroll
                for (int i = 0; i < 7; ++i)
                    stswz(Pb, g, 36 + e * 7 + i, 128, 0);
            }
        }
        __syncthreads();

        // o = P @ V
        {
            f32x4 oacc[3] = {fzero, fzero, fzero};
            #pragma unroll
            for (int ks = 0; ks < 2; ++ks) {
                bf16x8 b = ldfrag(Vt, wid * 16 + lr, ks * 64 + kbse, 128);
                #pragma unroll
                for (int mt = 0; mt < 3; ++mt) {
                    bf16x8 a = ldfrag(Pb, mt * 16 + lr, ks * 64 + kbse, 128);
                    oacc[mt] = mfma16(a, b, oacc[mt]);
                }
            }
            int col = h * 64 + wid * 16 + lr;
            #pragma unroll
            for (int mt = 0; mt < 3; ++mt)
                #pragma unroll
                for (int j = 0; j < 4; ++j)
                    stswz(Hb, mt * 16 + lg * 4 + j, col, 256, f2bf(oacc[mt][j]));
        }
        __syncthreads();
    }

    // out-proj + residual + in-register LN1
    float z[3][2][4];
    {
        f32x4 pacc[3][2];
        #pragma unroll
        for (int m = 0; m < 3; ++m) { pacc[m][0] = fzero; pacc[m][1] = fzero; }
        #pragma unroll
        for (int ks = 0; ks < 4; ++ks) {
            bf16x8 a0 = ldfrag(Hb,      lr, ks * 64 + kbse, 256);
            bf16x8 a1 = ldfrag(Hb, 16 + lr, ks * 64 + kbse, 256);
            bf16x8 a2 = ldfrag(Hb, 32 + lr, ks * 64 + kbse, 256);
            #pragma unroll
            for (int t = 0; t < 2; ++t) {
                bf16x8 b = ldfragG(opwb, (wid * 2 + t) * 16 + lr, ks * 64 + kbse, 256);
                pacc[0][t] = mfma16(a0, b, pacc[0][t]);
                pacc[1][t] = mfma16(a1, b, pacc[1][t]);
                pacc[2][t] = mfma16(a2, b, pacc[2][t]);
            }
        }
        #pragma unroll
        for (int t = 0; t < 2; ++t) {
            int col = (wid * 2 + t) * 16 + lr;
            float bias = opb[col];
            #pragma unroll
            for (int mt = 0; mt < 3; ++mt)
                #pragma unroll
                for (int j = 0; j < 4; ++j) {
                    int r = mt * 16 + lg * 4 + j;
                    z[mt][t][j] = (r < 36) ? pacc[mt][t][j] + bias + sg[r * 128 + col] : 0.f;
                }
        }
    }
    {
        float* part = scf;
        #pragma unroll
        for (int mt = 0; mt < 3; ++mt)
            #pragma unroll
            for (int j = 0; j < 4; ++j) {
                int r = mt * 16 + lg * 4 + j;
                float s  = z[mt][0][j] + z[mt][1][j];
                float ss = z[mt][0][j] * z[mt][0][j] + z[mt][1][j] * z[mt][1][j];
                s  += __shfl_xor(s, 1);  s  += __shfl_xor(s, 2);
                s  += __shfl_xor(s, 4);  s  += __shfl_xor(s, 8);
                ss += __shfl_xor(ss, 1); ss += __shfl_xor(ss, 2);
                ss += __shfl_xor(ss, 4); ss += __shfl_xor(ss, 8);
                if (lr == 0 && r < 36) { part[r * 8 + wid] = s; part[r * 8 + 4 + wid] = ss; }
            }
    }
    __syncthreads();
    {
        const float* part = scf;
        #pragma unroll
        for (int mt = 0; mt < 3; ++mt)
            #pragma unroll
            for (int j = 0; j < 4; ++j) {
                int r = mt * 16 + lg * 4 + j;
                if (r < 36) {
                    float s  = part[r * 8 + 0] + part[r * 8 + 1] + part[r * 8 + 2] + part[r * 8 + 3];
                    float ss = part[r * 8 + 4] + part[r * 8 + 5] + part[r * 8 + 6] + part[r * 8 + 7];
                    float mean = s * (1.f / 128.f);
                    float rstd = rsqrtf(ss * (1.f / 128.f) - mean * mean + EPSV);
                    #pragma unroll
                    for (int t = 0; t < 2; ++t) {
                        int col = (wid * 2 + t) * 16 + lr;
                        float v = (z[mt][t][j] - mean) * rstd * l1g[col] + l1b[col];
                        sg[r * 128 + col] = v;
                    }
                }
            }
    }
}

// ---------------------------------------------------------------------------
// FFN v2: all-register H (swapped FFN1 + permuted W2), zero barriers in the
// main loop. M=32 rows/block, grid 1152. Waves own disjoint 32-neuron groups;
// partial O reduced cross-wave in LDS at the end; fused LN2.
// ---------------------------------------------------------------------------
__global__ __launch_bounds__(256, 2) void ffn_reg(
    float* __restrict__ sres,
    const short* __restrict__ fw1b, const float* __restrict__ fb1,
    const short* __restrict__ fw2p, const float* __restrict__ fb2,
    const float* __restrict__ l2g, const float* __restrict__ l2b)
{
    __shared__ short Ab[32 * 128] __attribute__((aligned(16)));
    __shared__ float Of[32 * 132];

    const int tid  = threadIdx.x;
    const int wid  = tid >> 6;
    const int lane = tid & 63;
    const int lr   = lane & 15;
    const int lg   = lane >> 4;
    const size_t row0 = (size_t)blockIdx.x * 32;
    const f32x4 fzero = {0.f, 0.f, 0.f, 0.f};

    // stage A: 32x128 f32 -> bf16 swizzled
    for (int u = tid; u < 1024; u += 256) {
        int r = u >> 5, c4 = (u & 31) * 4;
        float4 v = *(const float4*)(sres + (row0 + r) * 128 + c4);
        short4 s4;
        s4.x = f2bf(v.x); s4.y = f2bf(v.y); s4.z = f2bf(v.z); s4.w = f2bf(v.w);
        int byte = r * 256 + ((c4 * 2) ^ ((r & 7) << 4));
        *(short4*)((char*)Ab + byte) = s4;
    }
    __syncthreads();

    // persistent S fragments (B-operand of swapped FFN1): S[rt*16+lr][k]
    bf16x8 sfrag[2][4];
    #pragma unroll
    for (int rt = 0; rt < 2; ++rt)
        #pragma unroll
        for (int ks = 0; ks < 4; ++ks)
            sfrag[rt][ks] = ldfrag(Ab, rt * 16 + lr, ks * 64 + lg * 16, 256);

    f32x4 facc[8][2];
    #pragma unroll
    for (int ct = 0; ct < 8; ++ct) { facc[ct][0] = fzero; facc[ct][1] = fzero; }

    // prefetch W1 A-frags for q=0: W1[nbase + nt*16 + lr][k]
    bf16x8 p1[2][4];
    #pragma unroll
    for (int nt = 0; nt < 2; ++nt)
        #pragma unroll
        for (int ks = 0; ks < 4; ++ks)
            p1[nt][ks] = ldfragG(fw1b, wid * 32 + nt * 16 + lr, ks * 64 + lg * 16, 256);

    #pragma unroll 1
    for (int q = 0; q < 16; ++q) {
        const int grp   = q * 4 + wid;
        const int nbase = grp * 32;

        // prefetch permuted W2 B-frags (lands under FFN1 MFMAs)
        bf16x8 p2[8];
        #pragma unroll
        for (int ct = 0; ct < 8; ++ct)
            p2[ct] = *(const bf16x8*)(fw2p +
                     ((size_t)(grp * 128 + ct * 16 + lr) * 4 + lg) * 8);
        float4 b1lo = *(const float4*)(fb1 + nbase + lg * 4);
        float4 b1hi = *(const float4*)(fb1 + nbase + 16 + lg * 4);

        // FFN1 (swapped): H^T = W1 . S^T ; lane holds H[r=rt*16+lr][n=nt*16+lg*4+j]
        f32x4 hacc[2][2];
        #pragma unroll
        for (int a = 0; a < 2; ++a) { hacc[a][0] = fzero; hacc[a][1] = fzero; }
        #pragma unroll
        for (int ks = 0; ks < 4; ++ks)
            #pragma unroll
            for (int nt = 0; nt < 2; ++nt) {
                hacc[nt][0] = mfma16(p1[nt][ks], sfrag[0][ks], hacc[nt][0]);
                hacc[nt][1] = mfma16(p1[nt][ks], sfrag[1][ks], hacc[nt][1]);
            }

        // prefetch next chunk's W1 (lands under FFN2 MFMAs)
        if (q < 15) {
            #pragma unroll
            for (int nt = 0; nt < 2; ++nt)
                #pragma unroll
                for (int ks = 0; ks < 4; ++ks)
                    p1[nt][ks] = ldfragG(fw1b,
                        (q + 1) * 128 + wid * 32 + nt * 16 + lr,
                        ks * 64 + lg * 16, 256);
        }

        // pack H A-frags in-register: slot s <-> n = (s>>2)*16 + lg*4 + (s&3)
        bf16x8 hf[2];
        #pragma unroll
        for (int mt = 0; mt < 2; ++mt) {
            bf16x8 h;
            h[0] = f2bf(fmaxf(hacc[0][mt][0] + b1lo.x, 0.f));
            h[1] = f2bf(fmaxf(hacc[0][mt][1] + b1lo.y, 0.f));
            h[2] = f2bf(fmaxf(hacc[0][mt][2] + b1lo.z, 0.f));
            h[3] = f2bf(fmaxf(hacc[0][mt][3] + b1lo.w, 0.f));
            h[4] = f2bf(fmaxf(hacc[1][mt][0] + b1hi.x, 0.f));
            h[5] = f2bf(fmaxf(hacc[1][mt][1] + b1hi.y, 0.f));
            h[6] = f2bf(fmaxf(hacc[1][mt][2] + b1hi.z, 0.f));
            h[7] = f2bf(fmaxf(hacc[1][mt][3] + b1hi.w, 0.f));
            hf[mt] = h;
        }

        // FFN2: O partial += H . W2^T  (k-slot map matches fw2p permutation)
        #pragma unroll
        for (int ct = 0; ct < 8; ++ct) {
            facc[ct][0] = mfma16(hf[0], p2[ct], facc[ct][0]);
            facc[ct][1] = mfma16(hf[1], p2[ct], facc[ct][1]);
        }
    }

    // cross-wave reduction of partial O (rotating disjoint 32-col blocks)
    for (int rr = 0; rr < 4; ++rr) {
        if (rr) __syncthreads();
        int u = (wid + rr) & 3;
        #pragma unroll
        for (int c2 = 0; c2 < 2; ++c2) {
            int ct = u * 2 + c2;
            #pragma unroll
            for (int mt = 0; mt < 2; ++mt)
                #pragma unroll
                for (int j = 0; j < 4; ++j) {
                    int r = mt * 16 + lg * 4 + j;
                    int c = ct * 16 + lr;
                    if (rr == 0) Of[r * 132 + c]  = facc[ct][mt][j];
                    else         Of[r * 132 + c] += facc[ct][mt][j];
                }
        }
    }
    __syncthreads();

    // LN2 + residual: 8 lanes per row, 16 cols each
    {
        int row = wid * 8 + (lane >> 3);
        int e   = lane & 7;
        const float* ofr = Of + row * 132 + e * 16;
        const float* rg  = sres + (row0 + row) * 128 + e * 16;
        float z16[16];
        float sum = 0.f, sq = 0.f;
        #pragma unroll
        for (int i = 0; i < 16; i += 4) {
            float4 o4 = *(const float4*)(ofr + i);
            float4 r4 = *(const float4*)(rg + i);
            float4 b4 = *(const float4*)(fb2 + e * 16 + i);
            float a0 = o4.x + b4.x + r4.x;
            float a1 = o4.y + b4.y + r4.y;
            float a2 = o4.z + b4.z + r4.z;
            float a3 = o4.w + b4.w + r4.w;
            z16[i] = a0; z16[i + 1] = a1; z16[i + 2] = a2; z16[i + 3] = a3;
            sum += a0 + a1 + a2 + a3;
            sq  += a0 * a0 + a1 * a1 + a2 * a2 + a3 * a3;
        }
        sum += __shfl_xor(sum, 1); sum += __shfl_xor(sum, 2); sum += __shfl_xor(sum, 4);
        sq  += __shfl_xor(sq, 1);  sq  += __shfl_xor(sq, 2);  sq  += __shfl_xor(sq, 4);
        float mean = sum * (1.f / 128.f);
        float rstd = rsqrtf(sq * (1.f / 128.f) - mean * mean + EPSV);
        float* og = sres + (row0 + row) * 128 + e * 16;
        #pragma unroll
        for (int i = 0; i < 16; i += 4) {
            float4 g4 = *(const float4*)(l2g + e * 16 + i);
            float4 bb = *(const float4*)(l2b + e * 16 + i);
            float4 o;
            o.x = (z16[i]     - mean) * rstd * g4.x + bb.x;
            o.y = (z16[i + 1] - mean) * rstd * g4.y + bb.y;
            o.z = (z16[i + 2] - mean) * rstd * g4.z + bb.z;
            o.w = (z16[i + 3] - mean) * rstd * g4.w + bb.w;
            *(float4*)(og + i) = o;
        }
    }
}

// ---------------------------------------------------------------------------
// pool + head (unchanged)
// ---------------------------------------------------------------------------
__global__ __launch_bounds__(128) void pool_head(
    const float* __restrict__ sbuf, const float* __restrict__ xgcn,
    const float* __restrict__ aww, const float* __restrict__ awb,
    const float* __restrict__ fcw, const float* __restrict__ fcb,
    float* __restrict__ out)
{
    __shared__ float sl[36][128];
    __shared__ float zz[36];
    __shared__ float p[128];
    int tid = threadIdx.x;
    int b = blockIdx.x;
    const float* sg = sbuf + (size_t)b * 4608;
    const float* gg = xgcn + (size_t)b * 4608;
    for (int idx = tid; idx < 4608; idx += 128)
        sl[0][idx] = sg[idx] + gg[idx];
    __syncthreads();
    if (tid < 36) {
        float acc = awb[0];
        #pragma unroll
        for (int j = 0; j < 128; j += 4) {
            float4 s4 = *(const float4*)&sl[tid][j];
            float4 w4 = *(const float4*)(aww + j);
            acc += s4.x * w4.x + s4.y * w4.y + s4.z * w4.z + s4.w * w4.w;
        }
        zz[tid] = acc;
    }
    __syncthreads();
    if (tid == 0) {
        float m = -1e30f;
        for (int k = 0; k < 36; ++k) m = fmaxf(m, zz[k]);
        float ssum = 0.f;
        for (int k = 0; k < 36; ++k) ssum += __expf(zz[k] - m);
        float inv = 1.f / ssum;
        for (int k = 0; k < 36; ++k) zz[k] = __expf(zz[k] - m) * inv;
    }
    __syncthreads();
    {
        float acc = 0.f;
        for (int l = 0; l < 36; ++l) acc += sl[l][tid] * zz[l];
        p[tid] = acc;
    }
    __syncthreads();
    if (tid == 0) {
        float acc = fcb[0];
        for (int dd = 0; dd < 128; ++dd) acc += p[dd] * fcw[dd];
        out[b] = acc >= 0.f ? acc : 0.1f * acc;
    }
}

// ---------------------------------------------------------------------------
extern "C" void kernel_launch(void* const* d_in, const int* in_sizes, int n_in,
                              void* d_out, int out_size, void* d_ws, size_t ws_size,
                              hipStream_t stream)
{
    const float* x   = (const float*)d_in[0];
    const float* Wg1 = (const float*)d_in[1];
    const float* bg1 = (const float*)d_in[2];
    const float* Wg2 = (const float*)d_in[3];
    const float* bg2 = (const float*)d_in[4];
    const float* c1w = (const float*)d_in[5];
    const float* c1b = (const float*)d_in[6];
    const float* c2w = (const float*)d_in[7];
    const float* c2b = (const float*)d_in[8];
    const float* bng = (const float*)d_in[9];
    const float* bnb = (const float*)d_in[10];
    const float* bnm = (const float*)d_in[11];
    const float* bnv = (const float*)d_in[12];
    const float* ipw = (const float*)d_in[13];
    const float* ipb = (const float*)d_in[14];
    const float* opw = (const float*)d_in[15];
    const float* opb = (const float*)d_in[16];
    const float* l1g = (const float*)d_in[17];
    const float* l1b = (const float*)d_in[18];
    const float* l2g = (const float*)d_in[19];
    const float* l2b = (const float*)d_in[20];
    const float* fw1 = (const float*)d_in[21];
    const float* fb1 = (const float*)d_in[22];
    const float* fw2 = (const float*)d_in[23];
    const float* fb2 = (const float*)d_in[24];
    const float* aww = (const float*)d_in[25];
    const float* awb = (const float*)d_in[26];
    const float* fcw = (const float*)d_in[27];
    const float* fcb = (const float*)d_in[28];
    float* out = (float*)d_out;

    float* sbuf = (float*)d_ws;                       // 1024*36*128 f32
    float* xgcn = sbuf + (size_t)1024 * 36 * 128;     // 1024*36*128 f32
    short* wb   = (short*)(xgcn + (size_t)1024 * 36 * 128);
    short* ipwb = wb;                  // 2*384*128
    short* opwb = wb + 98304;          // 2*128*128
    short* fw1b = wb + 131072;         // 2*2048*128
    short* fw2p = wb + 655360;         // 2*128*2048 (permuted)

    cvt_all<<<1152, 256, 0, stream>>>(ipw, opw, fw1, fw2, wb);
    gcn_all<<<18433, 256, 0, stream>>>(x, Wg1, bg1, Wg2, bg2, xgcn);
    conv_branch<<<1024, 256, 0, stream>>>(x, c1w, c1b, c2w, c2b,
                                          bng, bnb, bnm, bnv, sbuf);
    for (int i = 0; i < 2; ++i) {
        attn_mfma<<<1024, 256, 0, stream>>>(sbuf,
            ipwb + (size_t)i * 49152, ipb + (size_t)i * 384,
            opwb + (size_t)i * 16384, opb + (size_t)i * 128,
            l1g + (size_t)i * 128, l1b + (size_t)i * 128);
        ffn_reg<<<1152, 256, 0, stream>>>(sbuf,
            fw1b + (size_t)i * 262144, fb1 + (size_t)i * 2048,
            fw2p + (size_t)i * 262144, fb2 + (size_t)i * 128,
            l2g + (size_t)i * 128, l2b + (size_t)i * 128);
    }
    pool_head<<<1024, 128, 0, stream>>>(sbuf, xgcn, aww, awb, fcw, fcb, out);
}

// Round 8
// 358.249 us; speedup vs baseline: 1.2905x; 1.2888x over previous
//
#include <hip/hip_runtime.h>
#include <math.h>

#define EPSV   1e-5f

typedef __attribute__((ext_vector_type(8))) short bf16x8;
typedef __attribute__((ext_vector_type(4))) float f32x4;

__device__ __forceinline__ short f2bf(float f){
    unsigned u = __float_as_uint(f);
    u += 0x7fffu + ((u >> 16) & 1u);
    return (short)(u >> 16);
}
__device__ __forceinline__ f32x4 mfma16(bf16x8 a, bf16x8 b, f32x4 c){
    return __builtin_amdgcn_mfma_f32_16x16x32_bf16(a, b, c, 0, 0, 0);
}
__device__ __forceinline__ bf16x8 ldfrag(const short* base, int row, int kbyte, int rowBytes){
    int byte = row * rowBytes + kbyte;
    byte ^= (row & 7) << 4;
    return *(const bf16x8*)((const char*)base + byte);
}
__device__ __forceinline__ bf16x8 ldfragG(const short* base, int row, int kbyte, int rowBytes){
    return *(const bf16x8*)((const char*)base + (size_t)row * rowBytes + kbyte);
}
__device__ __forceinline__ void stswz(short* base, int row, int col, int rowBytes, short v){
    int byte = row * rowBytes + col * 2;
    byte ^= (row & 7) << 4;
    *(short*)((char*)base + byte) = v;
}

// ---------------------------------------------------------------------------
// one-shot fp32 -> bf16 weight conversion (unchanged from round 7).
// fw2p: fw2p[(((grp*128 + c)*4 + lg)*8 + s)] = W2[c][grp*32 + (s>>2)*16 + lg*4 + (s&3)]
// ---------------------------------------------------------------------------
__global__ __launch_bounds__(256) void cvt_all(
    const float* __restrict__ ipw, const float* __restrict__ opw,
    const float* __restrict__ fw1, const float* __restrict__ fw2,
    short* __restrict__ dst)
{
    int i = (blockIdx.x * 256 + threadIdx.x) * 4;
    if (i >= 1179648) return;
    const float* src; int off;
    if (i < 98304)       { src = ipw; off = i; }
    else if (i < 131072) { src = opw; off = i - 98304; }
    else if (i < 655360) { src = fw1; off = i - 131072; }
    else {
        int o  = i - 655360;
        int L  = o >> 18;
        int oo = o & 262143;
        int s0 = oo & 7;
        int lg = (oo >> 3) & 3;
        int c  = (oo >> 5) & 127;
        int grp = oo >> 12;
        int n  = grp * 32 + ((s0 >> 2) << 4) + lg * 4;
        src = fw2; off = L * 262144 + c * 2048 + n;
        float4 v = *(const float4*)(src + off);
        short4 s;
        s.x = f2bf(v.x); s.y = f2bf(v.y); s.z = f2bf(v.z); s.w = f2bf(v.w);
        *(short4*)(dst + i) = s;
        return;
    }
    float4 v = *(const float4*)(src + off);
    short4 s;
    s.x = f2bf(v.x); s.y = f2bf(v.y); s.z = f2bf(v.z); s.w = f2bf(v.w);
    *(short4*)(dst + i) = s;
}

// ---------------------------------------------------------------------------
// GCN branch (unchanged)
// ---------------------------------------------------------------------------
__global__ __launch_bounds__(256) void gcn_all(
    const float* __restrict__ x,
    const float* __restrict__ Wg1, const float* __restrict__ bg1,
    const float* __restrict__ Wg2, const float* __restrict__ bg2,
    float* __restrict__ xgcn)
{
    int tid = threadIdx.x;
    if (blockIdx.x == 18432) {
        __shared__ float xgm[9];
        __shared__ float h1s[64];
        if (tid < 9) {
            float s = 0.f;
            for (int r = 0; r < 9; ++r) {
                const float* xp = x + (r * 9 + tid) * 7;
                #pragma unroll
                for (int f = 0; f < 7; ++f) s += xp[f];
            }
            xgm[tid] = s * (1.f / 63.f);
        }
        __syncthreads();
        if (tid < 64) {
            float acc = bg1[tid];
            #pragma unroll
            for (int j = 0; j < 9; ++j) acc += xgm[j] * Wg1[j * 64 + tid];
            h1s[tid] = fmaxf(acc, 0.f);
        }
        __syncthreads();
        if (tid < 128) {
            float acc = bg2[tid];
            #pragma unroll 8
            for (int c = 0; c < 64; ++c) acc += h1s[c] * Wg2[c * 128 + tid];
            float v = fmaxf(acc, 0.f);
            for (int r = 0; r < 9; ++r) xgcn[r * 128 + tid] = v;
        }
        return;
    }

    __shared__ float xg[2][9];
    __shared__ float h1[2][64];
    int ri = tid >> 7;
    int tr = tid & 127;
    int row = blockIdx.x * 2 + ri;

    if (tr < 9) {
        const float* xp = x + (row * 9 + tr) * 7;
        float s = 0.f;
        #pragma unroll
        for (int f = 0; f < 7; ++f) s += xp[f];
        xg[ri][tr] = s * (1.f / 7.f);
    }
    __syncthreads();
    if (tr < 64) {
        float acc = bg1[tr];
        #pragma unroll
        for (int j = 0; j < 9; ++j) acc += xg[ri][j] * Wg1[j * 64 + tr];
        h1[ri][tr] = fmaxf(acc, 0.f);
    }
    __syncthreads();
    if (row >= 9) {
        float acc = bg2[tr];
        #pragma unroll 8
        for (int c = 0; c < 64; ++c) acc += h1[ri][c] * Wg2[c * 128 + tr];
        xgcn[row * 128 + tr] = fmaxf(acc, 0.f);
    }
}

// ---------------------------------------------------------------------------
// Conv branch (unchanged)
// ---------------------------------------------------------------------------
__global__ __launch_bounds__(256) void conv_branch(
    const float* __restrict__ x,
    const float* __restrict__ w1, const float* __restrict__ cb1,
    const float* __restrict__ w2, const float* __restrict__ cb2,
    const float* __restrict__ bng, const float* __restrict__ bnb,
    const float* __restrict__ bnm, const float* __restrict__ bnv,
    float* __restrict__ sbuf)
{
    __shared__ float xm[7 * 40];
    __shared__ float w1s[64 * 35];
    __shared__ float o1[64 * 38];
    int tid = threadIdx.x;
    int b = blockIdx.x;

    for (int idx = tid; idx < 7 * 40; idx += 256) xm[idx] = 0.f;
    for (int idx = tid; idx < 64 * 38; idx += 256) o1[idx] = 0.f;
    for (int idx = tid; idx < 2240; idx += 256) w1s[idx] = w1[idx];
    __syncthreads();

    const float* xb = x + (size_t)b * 2268;
    for (int idx = tid; idx < 252; idx += 256) {
        int f = idx / 36, l = idx - f * 36;
        float s = 0.f;
        #pragma unroll
        for (int n = 0; n < 9; ++n) s += xb[n * 252 + idx];
        xm[f * 40 + l + 2] = s * (1.f / 9.f);
    }
    __syncthreads();

    {
        int o = tid & 63, lh = tid >> 6;
        int l0 = lh * 9;
        float acc[9];
        float bias = cb1[o];
        #pragma unroll
        for (int r = 0; r < 9; ++r) acc[r] = bias;
        #pragma unroll
        for (int i = 0; i < 7; ++i) {
            #pragma unroll
            for (int k = 0; k < 5; ++k) {
                float w = w1s[o * 35 + i * 5 + k];
                const float* xrow = &xm[i * 40 + l0 + k];
                #pragma unroll
                for (int r = 0; r < 9; ++r) acc[r] += w * xrow[r];
            }
        }
        #pragma unroll
        for (int r = 0; r < 9; ++r) o1[o * 38 + l0 + r + 1] = acc[r];
    }
    __syncthreads();

    {
        int c = tid & 127, lh = tid >> 7;
        int l0 = lh * 18;
        float acc[18];
        #pragma unroll
        for (int r = 0; r < 18; ++r) acc[r] = 0.f;
        const float* w2c = w2 + c * 192;
        for (int i = 0; i < 64; ++i) {
            float wa = w2c[i * 3 + 0], wb = w2c[i * 3 + 1], wc = w2c[i * 3 + 2];
            const float* orow = &o1[i * 38 + l0];
            #pragma unroll
            for (int r = 0; r < 18; ++r)
                acc[r] += wa * orow[r] + wb * orow[r + 1] + wc * orow[r + 2];
        }
        float scale = bng[c] * rsqrtf(bnv[c] + EPSV);
        float shift = bnb[c] - bnm[c] * scale;
        float bias  = cb2[c];
        float* sb = sbuf + ((size_t)b * 36 + l0) * 128 + c;
        #pragma unroll
        for (int r = 0; r < 18; ++r)
            sb[r * 128] = (acc[r] + bias) * scale + shift;
    }
}

// ---------------------------------------------------------------------------
// Attention + out-proj + residual + LN1 (unchanged)
// ---------------------------------------------------------------------------
__global__ __launch_bounds__(256, 2) void attn_mfma(
    float* __restrict__ sbuf,
    const short* __restrict__ ipwb, const float* __restrict__ ipb,
    const short* __restrict__ opwb, const float* __restrict__ opb,
    const float* __restrict__ l1g, const float* __restrict__ l1b)
{
    __shared__ short Sb[48 * 128] __attribute__((aligned(16)));
    __shared__ char  U[38912]     __attribute__((aligned(16)));
    __shared__ float scf[36 * 40];
    short* Qb = (short*)U;
    short* Kb = (short*)(U + 6144);
    short* Vt = (short*)(U + 12288);
    short* Pb = (short*)(U + 20480);
    short* Hb = (short*)(U + 26624);

    const int tid  = threadIdx.x;
    const int wid  = tid >> 6;
    const int lane = tid & 63;
    const int lr   = lane & 15;
    const int lg   = lane >> 4;
    const int kbse = lg * 16;

    float* sg = sbuf + (size_t)blockIdx.x * 4608;
    const f32x4 fzero = {0.f, 0.f, 0.f, 0.f};

    for (int idx = tid; idx < 4608; idx += 256) {
        int r = idx >> 7, c = idx & 127;
        stswz(Sb, r, c, 256, f2bf(sg[idx]));
    }
    for (int idx = tid; idx < 1536; idx += 256)
        stswz(Sb, 36 + (idx >> 7), idx & 127, 256, 0);
    for (int idx = tid; idx < 1024; idx += 256)
        stswz(Vt, idx >> 4, 48 + (idx & 15), 128, 0);
    for (int idx = tid; idx < 768; idx += 256)
        stswz(Pb, 36 + (idx >> 6), idx & 63, 128, 0);
    __syncthreads();

    for (int h = 0; h < 2; ++h) {
        {
            f32x4 acc[3][3];
            #pragma unroll
            for (int a = 0; a < 3; ++a)
                #pragma unroll
                for (int m = 0; m < 3; ++m) acc[a][m] = fzero;
            const int wrow0 = h * 64 + wid * 16 + lr;
            #pragma unroll
            for (int ks = 0; ks < 4; ++ks) {
                bf16x8 a0 = ldfrag(Sb,      lr, ks * 64 + kbse, 256);
                bf16x8 a1 = ldfrag(Sb, 16 + lr, ks * 64 + kbse, 256);
                bf16x8 a2 = ldfrag(Sb, 32 + lr, ks * 64 + kbse, 256);
                #pragma unroll
                for (int mat = 0; mat < 3; ++mat) {
                    bf16x8 bf = ldfragG(ipwb, mat * 128 + wrow0, ks * 64 + kbse, 256);
                    acc[mat][0] = mfma16(a0, bf, acc[mat][0]);
                    acc[mat][1] = mfma16(a1, bf, acc[mat][1]);
                    acc[mat][2] = mfma16(a2, bf, acc[mat][2]);
                }
            }
            int col = wid * 16 + lr;
            #pragma unroll
            for (int mat = 0; mat < 3; ++mat) {
                float bias = ipb[mat * 128 + h * 64 + col];
                #pragma unroll
                for (int mt = 0; mt < 3; ++mt) {
                    f32x4 c4 = acc[mat][mt];
                    if (mat == 0) {
                        #pragma unroll
                        for (int j = 0; j < 4; ++j)
                            stswz(Qb, mt * 16 + lg * 4 + j, col, 128, f2bf(c4[j] + bias));
                    } else if (mat == 1) {
                        #pragma unroll
                        for (int j = 0; j < 4; ++j)
                            stswz(Kb, mt * 16 + lg * 4 + j, col, 128, f2bf(c4[j] + bias));
                    } else {
                        int rbase = mt * 16 + lg * 4;
                        short4 s4;
                        s4.x = f2bf(rbase + 0 < 36 ? c4[0] + bias : 0.f);
                        s4.y = f2bf(rbase + 1 < 36 ? c4[1] + bias : 0.f);
                        s4.z = f2bf(rbase + 2 < 36 ? c4[2] + bias : 0.f);
                        s4.w = f2bf(rbase + 3 < 36 ? c4[3] + bias : 0.f);
                        int byte = col * 128 + rbase * 2;
                        byte ^= (col & 7) << 4;
                        *(short4*)((char*)Vt + byte) = s4;
                    }
                }
            }
        }
        __syncthreads();

        for (int t = wid; t < 9; t += 4) {
            int mt = t / 3, nt = t - mt * 3;
            f32x4 acc = fzero;
            #pragma unroll
            for (int ks = 0; ks < 2; ++ks) {
                bf16x8 a = ldfrag(Qb, mt * 16 + lr, ks * 64 + kbse, 128);
                bf16x8 b = ldfrag(Kb, nt * 16 + lr, ks * 64 + kbse, 128);
                acc = mfma16(a, b, acc);
            }
            int col = nt * 16 + lr;
            if (col < 36) {
                #pragma unroll
                for (int j = 0; j < 4; ++j) {
                    int r = mt * 16 + lg * 4 + j;
                    if (r < 36) scf[r * 40 + col] = acc[j] * 0.125f;
                }
            }
        }
        __syncthreads();

        {
            int g = tid >> 2, e = tid & 3;
            if (g < 36) {
                float v[9];
                float mx = -1e30f;
                #pragma unroll
                for (int i = 0; i < 9; ++i) { v[i] = scf[g * 40 + e * 9 + i]; mx = fmaxf(mx, v[i]); }
                mx = fmaxf(mx, __shfl_xor(mx, 1));
                mx = fmaxf(mx, __shfl_xor(mx, 2));
                float ssum = 0.f;
                #pragma unroll
                for (int i = 0; i < 9; ++i) { v[i] = __expf(v[i] - mx); ssum += v[i]; }
                ssum += __shfl_xor(ssum, 1);
                ssum += __shfl_xor(ssum, 2);
                float inv = 1.f / ssum;
                #pragma unroll
                for (int i = 0; i < 9; ++i)
                    stswz(Pb, g, e * 9 + i, 128, f2bf(v[i] * inv));
                #pragma unroll
                for (int i = 0; i < 7; ++i)
                    stswz(Pb, g, 36 + e * 7 + i, 128, 0);
            }
        }
        __syncthreads();

        {
            f32x4 oacc[3] = {fzero, fzero, fzero};
            #pragma unroll
            for (int ks = 0; ks < 2; ++ks) {
                bf16x8 b = ldfrag(Vt, wid * 16 + lr, ks * 64 + kbse, 128);
                #pragma unroll
                for (int mt = 0; mt < 3; ++mt) {
                    bf16x8 a = ldfrag(Pb, mt * 16 + lr, ks * 64 + kbse, 128);
                    oacc[mt] = mfma16(a, b, oacc[mt]);
                }
            }
            int col = h * 64 + wid * 16 + lr;
            #pragma unroll
            for (int mt = 0; mt < 3; ++mt)
                #pragma unroll
                for (int j = 0; j < 4; ++j)
                    stswz(Hb, mt * 16 + lg * 4 + j, col, 256, f2bf(oacc[mt][j]));
        }
        __syncthreads();
    }

    float z[3][2][4];
    {
        f32x4 pacc[3][2];
        #pragma unroll
        for (int m = 0; m < 3; ++m) { pacc[m][0] = fzero; pacc[m][1] = fzero; }
        #pragma unroll
        for (int ks = 0; ks < 4; ++ks) {
            bf16x8 a0 = ldfrag(Hb,      lr, ks * 64 + kbse, 256);
            bf16x8 a1 = ldfrag(Hb, 16 + lr, ks * 64 + kbse, 256);
            bf16x8 a2 = ldfrag(Hb, 32 + lr, ks * 64 + kbse, 256);
            #pragma unroll
            for (int t = 0; t < 2; ++t) {
                bf16x8 b = ldfragG(opwb, (wid * 2 + t) * 16 + lr, ks * 64 + kbse, 256);
                pacc[0][t] = mfma16(a0, b, pacc[0][t]);
                pacc[1][t] = mfma16(a1, b, pacc[1][t]);
                pacc[2][t] = mfma16(a2, b, pacc[2][t]);
            }
        }
        #pragma unroll
        for (int t = 0; t < 2; ++t) {
            int col = (wid * 2 + t) * 16 + lr;
            float bias = opb[col];
            #pragma unroll
            for (int mt = 0; mt < 3; ++mt)
                #pragma unroll
                for (int j = 0; j < 4; ++j) {
                    int r = mt * 16 + lg * 4 + j;
                    z[mt][t][j] = (r < 36) ? pacc[mt][t][j] + bias + sg[r * 128 + col] : 0.f;
                }
        }
    }
    {
        float* part = scf;
        #pragma unroll
        for (int mt = 0; mt < 3; ++mt)
            #pragma unroll
            for (int j = 0; j < 4; ++j) {
                int r = mt * 16 + lg * 4 + j;
                float s  = z[mt][0][j] + z[mt][1][j];
                float ss = z[mt][0][j] * z[mt][0][j] + z[mt][1][j] * z[mt][1][j];
                s  += __shfl_xor(s, 1);  s  += __shfl_xor(s, 2);
                s  += __shfl_xor(s, 4);  s  += __shfl_xor(s, 8);
                ss += __shfl_xor(ss, 1); ss += __shfl_xor(ss, 2);
                ss += __shfl_xor(ss, 4); ss += __shfl_xor(ss, 8);
                if (lr == 0 && r < 36) { part[r * 8 + wid] = s; part[r * 8 + 4 + wid] = ss; }
            }
    }
    __syncthreads();
    {
        const float* part = scf;
        #pragma unroll
        for (int mt = 0; mt < 3; ++mt)
            #pragma unroll
            for (int j = 0; j < 4; ++j) {
                int r = mt * 16 + lg * 4 + j;
                if (r < 36) {
                    float s  = part[r * 8 + 0] + part[r * 8 + 1] + part[r * 8 + 2] + part[r * 8 + 3];
                    float ss = part[r * 8 + 4] + part[r * 8 + 5] + part[r * 8 + 6] + part[r * 8 + 7];
                    float mean = s * (1.f / 128.f);
                    float rstd = rsqrtf(ss * (1.f / 128.f) - mean * mean + EPSV);
                    #pragma unroll
                    for (int t = 0; t < 2; ++t) {
                        int col = (wid * 2 + t) * 16 + lr;
                        float v = (z[mt][t][j] - mean) * rstd * l1g[col] + l1b[col];
                        sg[r * 128 + col] = v;
                    }
                }
            }
    }
}

// ---------------------------------------------------------------------------
// FFN v3: LDS-staged weights (double-buffered, shared by all 4 waves),
// in-register H (swapped FFN1 + permuted W2), per-wave-complete output
// (no cross-wave reduce, no dynamic indexing anywhere), in-wave LN2.
// M=64 rows/block (16/wave), grid 576, 1 barrier per 64-neuron chunk.
// ---------------------------------------------------------------------------
__global__ __launch_bounds__(256, 2) void ffn_lds(
    float* __restrict__ sres,
    const short* __restrict__ fw1b, const float* __restrict__ fb1,
    const short* __restrict__ fw2p, const float* __restrict__ fb2,
    const float* __restrict__ l2g, const float* __restrict__ l2b)
{
    // per chunk: W1 16KB (64 n-rows x 256B, XOR-swizzled) + W2 16KB (frag-linear)
    __shared__ short Wbuf[2][16384] __attribute__((aligned(16)));   // 64 KB

    const int tid  = threadIdx.x;
    const int wid  = tid >> 6;
    const int lane = tid & 63;
    const int lr   = lane & 15;
    const int lg   = lane >> 4;
    const size_t row0 = (size_t)blockIdx.x * 64 + wid * 16;   // wave's rows
    const f32x4 fzero = {0.f, 0.f, 0.f, 0.f};

    // ---- persistent S fragments (B-operand; rows = wave's 16 rows) ----
    bf16x8 sfrag[4];
    {
        const float* sp = sres + (row0 + lr) * 128;
        #pragma unroll
        for (int ks = 0; ks < 4; ++ks) {
            float4 lo = *(const float4*)(sp + ks * 32 + lg * 8);
            float4 hi = *(const float4*)(sp + ks * 32 + lg * 8 + 4);
            bf16x8 f;
            f[0] = f2bf(lo.x); f[1] = f2bf(lo.y); f[2] = f2bf(lo.z); f[3] = f2bf(lo.w);
            f[4] = f2bf(hi.x); f[5] = f2bf(hi.y); f[6] = f2bf(hi.z); f[7] = f2bf(hi.w);
            sfrag[ks] = f;
        }
    }

    f32x4 facc[8];
    #pragma unroll
    for (int ct = 0; ct < 8; ++ct) facc[ct] = fzero;

    // ---- staging: 8 x 16B per thread per chunk; global reads are linear ----
    bf16x8 g1[4], g2[4];
    #pragma unroll
    for (int i2 = 0; i2 < 4; ++i2) {
        int fid = tid + 256 * i2;
        g1[i2] = *(const bf16x8*)((const char*)fw1b + fid * 16);
        g2[i2] = *(const bf16x8*)((const char*)fw2p + fid * 16);
    }
    #pragma unroll
    for (int i2 = 0; i2 < 4; ++i2) {
        int fid = tid + 256 * i2;
        int swz = (fid * 16) ^ ((((fid >> 4) & 7)) << 4);
        *(bf16x8*)((char*)&Wbuf[0][0] + swz)          = g1[i2];
        *(bf16x8*)((char*)&Wbuf[0][8192] + fid * 16)  = g2[i2];
    }

    #pragma unroll 2
    for (int q = 0; q < 32; ++q) {
        // issue next chunk's loads (async; land under this chunk's compute)
        if (q < 31) {
            const char* b1p = (const char*)fw1b + (q + 1) * 16384;
            const char* b2p = (const char*)fw2p + (q + 1) * 16384;
            #pragma unroll
            for (int i2 = 0; i2 < 4; ++i2) {
                int fid = tid + 256 * i2;
                g1[i2] = *(const bf16x8*)(b1p + fid * 16);
                g2[i2] = *(const bf16x8*)(b2p + fid * 16);
            }
        }
        __syncthreads();   // buf[q&1] writes (prev iter) visible to all waves
        const short* W1l = &Wbuf[q & 1][0];
        const short* W2l = &Wbuf[q & 1][8192];

        // FFN1 (swapped): A = W1 frag (LDS), B = sfrag -> H^T in regs
        f32x4 hacc[4];
        #pragma unroll
        for (int nt = 0; nt < 4; ++nt) hacc[nt] = fzero;
        #pragma unroll
        for (int ks = 0; ks < 4; ++ks) {
            #pragma unroll
            for (int nt = 0; nt < 4; ++nt) {
                bf16x8 a = ldfrag(W1l, nt * 16 + lr, ks * 64 + lg * 16, 256);
                hacc[nt] = mfma16(a, sfrag[ks], hacc[nt]);
            }
        }

        // bias + relu + pack: slot s <-> n = ksn*32 + (s>>2)*16 + lg*4 + (s&3)
        const int nbase = q * 64;
        bf16x8 hf[2];
        #pragma unroll
        for (int ksn = 0; ksn < 2; ++ksn) {
            float4 bA = *(const float4*)(fb1 + nbase + ksn * 32 + lg * 4);
            float4 bB = *(const float4*)(fb1 + nbase + ksn * 32 + 16 + lg * 4);
            bf16x8 h;
            h[0] = f2bf(fmaxf(hacc[ksn * 2][0]     + bA.x, 0.f));
            h[1] = f2bf(fmaxf(hacc[ksn * 2][1]     + bA.y, 0.f));
            h[2] = f2bf(fmaxf(hacc[ksn * 2][2]     + bA.z, 0.f));
            h[3] = f2bf(fmaxf(hacc[ksn * 2][3]     + bA.w, 0.f));
            h[4] = f2bf(fmaxf(hacc[ksn * 2 + 1][0] + bB.x, 0.f));
            h[5] = f2bf(fmaxf(hacc[ksn * 2 + 1][1] + bB.y, 0.f));
            h[6] = f2bf(fmaxf(hacc[ksn * 2 + 1][2] + bB.z, 0.f));
            h[7] = f2bf(fmaxf(hacc[ksn * 2 + 1][3] + bB.w, 0.f));
            hf[ksn] = h;
        }

        // FFN2: A = hf (regs), B = W2 frag (LDS, permuted layout)
        #pragma unroll
        for (int ksn = 0; ksn < 2; ++ksn)
            #pragma unroll
            for (int ct = 0; ct < 8; ++ct) {
                bf16x8 b2 = *(const bf16x8*)(W2l +
                              ((ksn * 128 + ct * 16 + lr) * 4 + lg) * 8);
                facc[ct] = mfma16(hf[ksn], b2, facc[ct]);
            }

        // write staged chunk q+1 into the other buffer (safe: nobody reads it
        // until after the next barrier)
        if (q < 31) {
            char* d1 = (char*)&Wbuf[(q + 1) & 1][0];
            char* d2 = (char*)&Wbuf[(q + 1) & 1][8192];
            #pragma unroll
            for (int i2 = 0; i2 < 4; ++i2) {
                int fid = tid + 256 * i2;
                int swz = (fid * 16) ^ ((((fid >> 4) & 7)) << 4);
                *(bf16x8*)(d1 + swz)        = g1[i2];
                *(bf16x8*)(d2 + fid * 16)   = g2[i2];
            }
        }
    }

    // ---- epilogue: + b2 + residual, in-wave LN2, write back ----
    // facc[ct] lane(lr,lg) reg j = O[row0 + lg*4 + j][ct*16 + lr]
    float zv[8][4];
    #pragma unroll
    for (int ct = 0; ct < 8; ++ct) {
        int c = ct * 16 + lr;
        float b2v = fb2[c];
        #pragma unroll
        for (int j = 0; j < 4; ++j)
            zv[ct][j] = facc[ct][j] + b2v + sres[(row0 + lg * 4 + j) * 128 + c];
    }
    #pragma unroll
    for (int j = 0; j < 4; ++j) {
        float s = 0.f, sq = 0.f;
        #pragma unroll
        for (int ct = 0; ct < 8; ++ct) { s += zv[ct][j]; sq += zv[ct][j] * zv[ct][j]; }
        s  += __shfl_xor(s, 1);  s  += __shfl_xor(s, 2);
        s  += __shfl_xor(s, 4);  s  += __shfl_xor(s, 8);
        sq += __shfl_xor(sq, 1); sq += __shfl_xor(sq, 2);
        sq += __shfl_xor(sq, 4); sq += __shfl_xor(sq, 8);
        float mean = s * (1.f / 128.f);
        float rstd = rsqrtf(sq * (1.f / 128.f) - mean * mean + EPSV);
        float* og = sres + (row0 + lg * 4 + j) * 128;
        #pragma unroll
        for (int ct = 0; ct < 8; ++ct) {
            int c = ct * 16 + lr;
            og[c] = (zv[ct][j] - mean) * rstd * l2g[c] + l2b[c];
        }
    }
}

// ---------------------------------------------------------------------------
// pool + head (unchanged)
// ---------------------------------------------------------------------------
__global__ __launch_bounds__(128) void pool_head(
    const float* __restrict__ sbuf, const float* __restrict__ xgcn,
    const float* __restrict__ aww, const float* __restrict__ awb,
    const float* __restrict__ fcw, const float* __restrict__ fcb,
    float* __restrict__ out)
{
    __shared__ float sl[36][128];
    __shared__ float zz[36];
    __shared__ float p[128];
    int tid = threadIdx.x;
    int b = blockIdx.x;
    const float* sg = sbuf + (size_t)b * 4608;
    const float* gg = xgcn + (size_t)b * 4608;
    for (int idx = tid; idx < 4608; idx += 128)
        sl[0][idx] = sg[idx] + gg[idx];
    __syncthreads();
    if (tid < 36) {
        float acc = awb[0];
        #pragma unroll
        for (int j = 0; j < 128; j += 4) {
            float4 s4 = *(const float4*)&sl[tid][j];
            float4 w4 = *(const float4*)(aww + j);
            acc += s4.x * w4.x + s4.y * w4.y + s4.z * w4.z + s4.w * w4.w;
        }
        zz[tid] = acc;
    }
    __syncthreads();
    if (tid == 0) {
        float m = -1e30f;
        for (int k = 0; k < 36; ++k) m = fmaxf(m, zz[k]);
        float ssum = 0.f;
        for (int k = 0; k < 36; ++k) ssum += __expf(zz[k] - m);
        float inv = 1.f / ssum;
        for (int k = 0; k < 36; ++k) zz[k] = __expf(zz[k] - m) * inv;
    }
    __syncthreads();
    {
        float acc = 0.f;
        for (int l = 0; l < 36; ++l) acc += sl[l][tid] * zz[l];
        p[tid] = acc;
    }
    __syncthreads();
    if (tid == 0) {
        float acc = fcb[0];
        for (int dd = 0; dd < 128; ++dd) acc += p[dd] * fcw[dd];
        out[b] = acc >= 0.f ? acc : 0.1f * acc;
    }
}

// ---------------------------------------------------------------------------
extern "C" void kernel_launch(void* const* d_in, const int* in_sizes, int n_in,
                              void* d_out, int out_size, void* d_ws, size_t ws_size,
                              hipStream_t stream)
{
    const float* x   = (const float*)d_in[0];
    const float* Wg1 = (const float*)d_in[1];
    const float* bg1 = (const float*)d_in[2];
    const float* Wg2 = (const float*)d_in[3];
    const float* bg2 = (const float*)d_in[4];
    const float* c1w = (const float*)d_in[5];
    const float* c1b = (const float*)d_in[6];
    const float* c2w = (const float*)d_in[7];
    const float* c2b = (const float*)d_in[8];
    const float* bng = (const float*)d_in[9];
    const float* bnb = (const float*)d_in[10];
    const float* bnm = (const float*)d_in[11];
    const float* bnv = (const float*)d_in[12];
    const float* ipw = (const float*)d_in[13];
    const float* ipb = (const float*)d_in[14];
    const float* opw = (const float*)d_in[15];
    const float* opb = (const float*)d_in[16];
    const float* l1g = (const float*)d_in[17];
    const float* l1b = (const float*)d_in[18];
    const float* l2g = (const float*)d_in[19];
    const float* l2b = (const float*)d_in[20];
    const float* fw1 = (const float*)d_in[21];
    const float* fb1 = (const float*)d_in[22];
    const float* fw2 = (const float*)d_in[23];
    const float* fb2 = (const float*)d_in[24];
    const float* aww = (const float*)d_in[25];
    const float* awb = (const float*)d_in[26];
    const float* fcw = (const float*)d_in[27];
    const float* fcb = (const float*)d_in[28];
    float* out = (float*)d_out;

    float* sbuf = (float*)d_ws;                       // 1024*36*128 f32
    float* xgcn = sbuf + (size_t)1024 * 36 * 128;     // 1024*36*128 f32
    short* wb   = (short*)(xgcn + (size_t)1024 * 36 * 128);
    short* ipwb = wb;                  // 2*384*128
    short* opwb = wb + 98304;          // 2*128*128
    short* fw1b = wb + 131072;         // 2*2048*128
    short* fw2p = wb + 655360;         // 2*128*2048 (permuted)

    cvt_all<<<1152, 256, 0, stream>>>(ipw, opw, fw1, fw2, wb);
    gcn_all<<<18433, 256, 0, stream>>>(x, Wg1, bg1, Wg2, bg2, xgcn);
    conv_branch<<<1024, 256, 0, stream>>>(x, c1w, c1b, c2w, c2b,
                                          bng, bnb, bnm, bnv, sbuf);
    for (int i = 0; i < 2; ++i) {
        attn_mfma<<<1024, 256, 0, stream>>>(sbuf,
            ipwb + (size_t)i * 49152, ipb + (size_t)i * 384,
            opwb + (size_t)i * 16384, opb + (size_t)i * 128,
            l1g + (size_t)i * 128, l1b + (size_t)i * 128);
        ffn_lds<<<576, 256, 0, stream>>>(sbuf,
            fw1b + (size_t)i * 262144, fb1 + (size_t)i * 2048,
            fw2p + (size_t)i * 262144, fb2 + (size_t)i * 128,
            l2g + (size_t)i * 128, l2b + (size_t)i * 128);
    }
    pool_head<<<1024, 128, 0, stream>>>(sbuf, xgcn, aww, awb, fcw, fcb, out);
}